// Round 10
// baseline (125.541 us; speedup 1.0000x reference)
//
#include <hip/hip_runtime.h>

#define HW 512
#define NSTATE (HW * HW)   // 262144
#define NC4_X 196608       // x as float4 (3*H*W/4)
#define NC4_POLROW 262144  // Wpol row stride in float4
#define NC4_V 65536        // v as float4

#define CH4 1024     // float4 per wave-chunk (16 KB)
#define NCH_X 192    // chunks per W1 row / per WpolX row
#define NCH_V 64     // chunks per WpolV row
#define SPAN_ROP 1024

// ws layout (float offsets)
#define WS_PART1 0             // 192*32
#define WS_PARTPX 6144         // 192*32
#define WS_PARTPV 12288        // 64*32
#define WS_H2 14336            // 64
#define WS_P 14400             // 262144
#define WS_RD (WS_P + NSTATE)
#define WS_V (WS_RD + NSTATE)

#define SGB __builtin_amdgcn_sched_group_barrier

__device__ __forceinline__ float wred(float a) {
  a += __shfl_xor(a, 32);
  a += __shfl_xor(a, 16);
  a += __shfl_xor(a, 8);
  a += __shfl_xor(a, 4);
  a += __shfl_xor(a, 2);
  a += __shfl_xor(a, 1);
  return a;
}

// One wave: dot of a contiguous 16 KB W span with the matching x span, both
// read straight from global as two 8-load bursts per half (single base +
// immediate offsets each). No LDS, no barrier.
__device__ __forceinline__ float span_dot(const float4* __restrict__ wp,
                                          const float4* __restrict__ xp) {
  float acc = 0.f;
#pragma unroll
  for (int bt = 0; bt < 2; ++bt) {
    float4 w[8], xv[8];
#pragma unroll
    for (int j = 0; j < 8; ++j) w[j] = wp[bt * 512 + j * 64];
#pragma unroll
    for (int j = 0; j < 8; ++j) xv[j] = xp[bt * 512 + j * 64];
    SGB(0x020, 16, 0);  // the 16-load cluster
#pragma unroll
    for (int j = 0; j < 8; ++j)
      acc += w[j].x * xv[j].x + w[j].y * xv[j].y + w[j].z * xv[j].z +
             w[j].w * xv[j].w;
  }
  return acc;
}

// ---------------------------------------------------------------------------
// K1: W1@x partials, FLAT-LINEAR decomposition (rop's address behavior):
// block b = b-th contiguous 64 KB chunk of W1 (rows contiguous -> row=b/48,
// cb=b%48); the 4 waves take ADJACENT 16 KB quarters (R3-R9 mv variants all
// put concurrent waves on rows 3-4 MB apart -> scattered-burst penalty, all
// pinned at ~2.5-3.3 TB/s regardless of micro-structure).
// x read per-wave from global (L2/L3-hot). 1536 blocks.
// ---------------------------------------------------------------------------
__global__ __launch_bounds__(256) void mv_w1(const float4* __restrict__ W1,
                                             const float4* __restrict__ x,
                                             float* __restrict__ part1) {
  int b = blockIdx.x;  // [0,1536)
  int row = b / 48, cb = b - row * 48;
  int tid = threadIdx.x, wave = tid >> 6, lane = tid & 63;
  int ch = cb * 4 + wave;  // chunk-in-row 0..191
  const float4* __restrict__ wp =
      W1 + (size_t)row * NC4_X + (size_t)ch * CH4 + lane;
  const float4* __restrict__ xp = x + (size_t)ch * CH4 + lane;
  float acc = span_dot(wp, xp);
  acc = wred(acc);
  if (lane == 0) part1[ch * 32 + row] = acc;
}

// ---------------------------------------------------------------------------
// finish_h: reduce part1[192][32] -> h1 = relu(W1@x+b1); h2 = relu(W2@h1+b2).
// ---------------------------------------------------------------------------
__global__ __launch_bounds__(1024) void finish_h(
    const float* __restrict__ partials, const float* __restrict__ b1,
    const float* __restrict__ W2, const float* __restrict__ b2,
    float* __restrict__ h2out) {
  __shared__ float red[32][32];
  __shared__ float h1[32];
  int tid = threadIdx.x;
  int row = tid & 31, grp = tid >> 5;
  float s = 0.f;
  for (int b = grp; b < NCH_X; b += 32) s += partials[b * 32 + row];
  red[grp][row] = s;
  __syncthreads();
  if (tid < 32) {
    float t = b1[tid];
    for (int g = 0; g < 32; ++g) t += red[g][tid];
    h1[tid] = fmaxf(t, 0.f);
  }
  __syncthreads();
  if (tid < 64) {
    float t = b2[tid];
    for (int k = 0; k < 32; ++k) t += W2[tid * 32 + k] * h1[k];
    h2out[tid] = fmaxf(t, 0.f);
  }
}

// ---------------------------------------------------------------------------
// K3 fused: blocks [0,1024) = rop (p, rd from h2 — R5's measured-fast shape,
// unchanged); blocks [1024,2560) = WpolX partials (need only x, not h2, so
// they ride under rop's stream instead of bloating the pre-h2 kernel).
// ---------------------------------------------------------------------------
__global__ __launch_bounds__(256) void ropx_kernel(
    const float4* __restrict__ Wro4, const float* __restrict__ bro,
    const float4* __restrict__ Wri4, const float* __restrict__ bri,
    const float4* __restrict__ Wp4, const float* __restrict__ bp,
    const float* __restrict__ h2, float* __restrict__ p_out,
    float* __restrict__ rd_out, const float4* __restrict__ Wpol,
    const float4* __restrict__ x, float* __restrict__ partPx) {
  __shared__ float dots[4][3][64];
  int tid = threadIdx.x;
  int wave = tid >> 6, lane = tid & 63;
  if (blockIdx.x >= 1024) {  // ---- polx path ----
    int bb = blockIdx.x - 1024;  // [0,1536)
    int row = bb / 48, cb = bb - row * 48;
    int ch = cb * 4 + wave;
    const float4* __restrict__ wp =
        Wpol + (size_t)row * NC4_POLROW + NC4_V + (size_t)ch * CH4 + lane;
    const float4* __restrict__ xp = x + (size_t)ch * CH4 + lane;
    float acc = span_dot(wp, xp);
    acc = wred(acc);
    if (lane == 0) partPx[ch * 32 + row] = acc;
    return;
  }
  // ---- rop path (R5, unchanged) ----
  int grp = lane >> 4;
  float4 h4 = ((const float4*)h2)[lane & 15];
  int span = blockIdx.x * 4 + wave;       // [0,4096)
  size_t base = (size_t)span * SPAN_ROP;  // first float4 of span
  const float4* mats[3] = {Wro4, Wri4, Wp4};
#pragma unroll
  for (int m = 0; m < 3; ++m) {
    const float4* __restrict__ W = mats[m] + base + lane;
#pragma unroll
    for (int batch = 0; batch < 2; ++batch) {
      float4 w[8];
#pragma unroll
      for (int j = 0; j < 8; ++j) w[j] = W[(batch * 8 + j) * 64];
      SGB(0x020, 8, 0);
      float part[8];
#pragma unroll
      for (int j = 0; j < 8; ++j)
        part[j] = w[j].x * h4.x + w[j].y * h4.y + w[j].z * h4.z + w[j].w * h4.w;
#pragma unroll
      for (int j = 0; j < 8; ++j) {
        part[j] += __shfl_xor(part[j], 8);
        part[j] += __shfl_xor(part[j], 4);
        part[j] += __shfl_xor(part[j], 2);
        part[j] += __shfl_xor(part[j], 1);
      }
      if ((lane & 15) == 0) {
#pragma unroll
        for (int j = 0; j < 8; ++j)
          dots[wave][m][(batch * 8 + j) * 4 + grp] = part[j];
      }
    }
  }
  __syncthreads();
  int o = blockIdx.x * 256 + tid;
  float dro = dots[tid >> 6][0][tid & 63] + bro[o];
  float dri = dots[tid >> 6][1][tid & 63] + bri[o];
  float dp = dots[tid >> 6][2][tid & 63] + bp[o];
  float sro = 1.f / (1.f + __expf(-dro));
  float sri = 1.f / (1.f + __expf(-dri));
  float pv = 1.f / (1.f + __expf(-dp));
  p_out[o] = pv;
  rd_out[o] = sri - sro;
}

// ---------------------------------------------------------------------------
// Value iteration, ONE launch, 1024 blocks. 16x16 tile + halo 10 in LDS,
// 10 local iterations; zero-padding semantics preserved.
// ---------------------------------------------------------------------------
#define TILE 16
#define HALO 10
#define LR 36  // TILE + 2*HALO
__global__ __launch_bounds__(256) void valiter_kernel(
    const float* __restrict__ p, const float* __restrict__ rd,
    float* __restrict__ vout) {
  __shared__ float u[LR + 2][LR + 3];
  __shared__ float pp[LR][LR + 1];
  __shared__ float rr[LR][LR + 1];
  __shared__ float vv[LR][LR + 1];
  int tid = threadIdx.x;
  int ti = blockIdx.x >> 5, tj = blockIdx.x & 31;
  int gi0 = ti * TILE - HALO, gj0 = tj * TILE - HALO;
  for (int idx = tid; idx < (LR + 2) * (LR + 3); idx += 256)
    ((float*)u)[idx] = 0.f;
  for (int idx = tid; idx < LR * LR; idx += 256) {
    int i = idx / LR, j = idx % LR;
    int gi = gi0 + i, gj = gj0 + j;
    bool ok = (gi >= 0) & (gi < HW) & (gj >= 0) & (gj < HW);
    pp[i][j] = ok ? p[gi * HW + gj] : 0.f;
    rr[i][j] = ok ? rd[gi * HW + gj] : 0.f;
    vv[i][j] = 0.f;
  }
  __syncthreads();
  for (int k = 0; k < 10; ++k) {
#pragma unroll
    for (int idx = tid; idx < LR * LR; idx += 256) {
      int i = idx / LR, j = idx % LR;
      u[i + 1][j + 1] = vv[i][j] * pp[i][j] + rr[i][j];
    }
    __syncthreads();
#pragma unroll
    for (int idx = tid; idx < LR * LR; idx += 256) {
      int i = idx / LR, j = idx % LR;
      float m = u[i][j];
      m = fmaxf(m, u[i][j + 1]);
      m = fmaxf(m, u[i][j + 2]);
      m = fmaxf(m, u[i + 1][j]);
      m = fmaxf(m, u[i + 1][j + 2]);
      m = fmaxf(m, u[i + 2][j]);
      m = fmaxf(m, u[i + 2][j + 1]);
      m = fmaxf(m, u[i + 2][j + 2]);
      vv[i][j] = m;
    }
    __syncthreads();
  }
  if (tid < TILE * TILE) {
    int a = tid >> 4, b = tid & 15;
    vout[(ti * TILE + a) * HW + tj * TILE + b] = vv[HALO + a][HALO + b];
  }
}

// ---------------------------------------------------------------------------
// K5: Wpol[:, v-cols] @ v partials, flat-linear like mv_w1. 512 blocks.
// ---------------------------------------------------------------------------
__global__ __launch_bounds__(256) void mv_polv(const float4* __restrict__ Wpol,
                                               const float4* __restrict__ v,
                                               float* __restrict__ partPv) {
  int b = blockIdx.x;  // [0,512)
  int row = b / 16, cb = b - row * 16;
  int tid = threadIdx.x, wave = tid >> 6, lane = tid & 63;
  int ch = cb * 4 + wave;  // 0..63
  const float4* __restrict__ wp =
      Wpol + (size_t)row * NC4_POLROW + (size_t)ch * CH4 + lane;
  const float4* __restrict__ xp = v + (size_t)ch * CH4 + lane;
  float acc = span_dot(wp, xp);
  acc = wred(acc);
  if (lane == 0) partPv[ch * 32 + row] = acc;
}

// ---------------------------------------------------------------------------
// finish_pol: hp = relu(bpol + sum partPx[192][32] + sum partPv[64][32]);
// logits = Whead@hp + bhead; softmax; out[8] = v[pos].
// ---------------------------------------------------------------------------
__global__ __launch_bounds__(1024) void finish_pol(
    const float* __restrict__ partPx, const float* __restrict__ partPv,
    const float* __restrict__ bpol, const float* __restrict__ Whead,
    const float* __restrict__ bhead, const float* __restrict__ v,
    const int* __restrict__ pos, float* __restrict__ out) {
  __shared__ float red[32][32];
  __shared__ float hp[32];
  __shared__ float logits[8];
  int tid = threadIdx.x;
  int row = tid & 31, grp = tid >> 5;
  float s = 0.f;
  for (int b = grp; b < NCH_X; b += 32) s += partPx[b * 32 + row];
  for (int b = grp; b < NCH_V; b += 32) s += partPv[b * 32 + row];
  red[grp][row] = s;
  __syncthreads();
  if (tid < 32) {
    float t = bpol[tid];
    for (int g = 0; g < 32; ++g) t += red[g][tid];
    hp[tid] = fmaxf(t, 0.f);
  }
  __syncthreads();
  if (tid < 8) {
    float t = bhead[tid];
    for (int k = 0; k < 32; ++k) t += Whead[tid * 32 + k] * hp[k];
    logits[tid] = t;
  }
  __syncthreads();
  if (tid == 0) {
    float mx = logits[0];
    for (int j = 1; j < 8; ++j) mx = fmaxf(mx, logits[j]);
    float e[8], sum = 0.f;
    for (int j = 0; j < 8; ++j) {
      e[j] = __expf(logits[j] - mx);
      sum += e[j];
    }
    for (int j = 0; j < 8; ++j) out[j] = e[j] / sum;
    out[8] = v[pos[0] * HW + pos[1]];
  }
}

extern "C" void kernel_launch(void* const* d_in, const int* in_sizes, int n_in,
                              void* d_out, int out_size, void* d_ws,
                              size_t ws_size, hipStream_t stream) {
  const float* x = (const float*)d_in[0];
  const int* pos = (const int*)d_in[1];
  const float* W1 = (const float*)d_in[2];
  const float* b1 = (const float*)d_in[3];
  const float* W2 = (const float*)d_in[4];
  const float* b2 = (const float*)d_in[5];
  const float* Wro = (const float*)d_in[6];
  const float* bro = (const float*)d_in[7];
  const float* Wri = (const float*)d_in[8];
  const float* bri = (const float*)d_in[9];
  const float* Wp = (const float*)d_in[10];
  const float* bp = (const float*)d_in[11];
  const float* Wpol = (const float*)d_in[12];
  const float* bpol = (const float*)d_in[13];
  const float* Whead = (const float*)d_in[14];
  const float* bhead = (const float*)d_in[15];
  float* ws = (float*)d_ws;
  float* out = (float*)d_out;

  float* part1 = ws + WS_PART1;
  float* partPx = ws + WS_PARTPX;
  float* partPv = ws + WS_PARTPV;
  float* h2 = ws + WS_H2;
  float* pbuf = ws + WS_P;
  float* rdbuf = ws + WS_RD;
  float* vbuf = ws + WS_V;

  // K1: W1@x partials only (flat-linear)
  mv_w1<<<1536, 256, 0, stream>>>((const float4*)W1, (const float4*)x, part1);
  // K2: h1 -> h2
  finish_h<<<1, 1024, 0, stream>>>(part1, b1, W2, b2, h2);
  // K3: rop (p, rd) + WpolX partials fused
  ropx_kernel<<<2560, 256, 0, stream>>>(
      (const float4*)Wro, bro, (const float4*)Wri, bri, (const float4*)Wp, bp,
      h2, pbuf, rdbuf, (const float4*)Wpol, (const float4*)x, partPx);
  // K4: 10 value-iteration steps, one launch
  valiter_kernel<<<1024, 256, 0, stream>>>(pbuf, rdbuf, vbuf);
  // K5: WpolV partials
  mv_polv<<<512, 256, 0, stream>>>((const float4*)Wpol, (const float4*)vbuf,
                                   partPv);
  // K6: heads + softmax + state value
  finish_pol<<<1, 1024, 0, stream>>>(partPx, partPv, bpol, Whead, bhead, vbuf,
                                     pos, out);
}